// Round 2
// baseline (483.256 us; speedup 1.0000x reference)
//
#include <hip/hip_runtime.h>
#include <math.h>

#define BATCH 256
#define NPTS  20000
#define NCHUNK 10
#define PERCH (NPTS / NCHUNK)   // 2000

// =====================================================================
// Phase 1: weighted 9x9 Gram accumulation (lower triangle, 45 entries)
// Lower triangle [i][j], i>=j:  sum_n X_i * (w * X_j)  -- matches
// einsum('bni,bnj->bij', X, w*X) lower triangle read by LAPACK UPLO='L'.
// =====================================================================
__global__ __launch_bounds__(256) void gram_kernel(
    const float4* __restrict__ x, const float* __restrict__ w,
    double* __restrict__ gram)
{
    int b = blockIdx.x;
    int chunk = blockIdx.y;
    int tid = threadIdx.x;

    float acc[45];
#pragma unroll
    for (int k = 0; k < 45; ++k) acc[k] = 0.0f;

    const float4* xb = x + (size_t)b * NPTS;
    const float*  wb = w + (size_t)b * NPTS;
    int base = chunk * PERCH;
    for (int n = base + tid; n < base + PERCH; n += 256) {
        float4 v = xb[n];
        float wt = wb[n];
        float X[9];
        X[0] = v.z * v.x; X[1] = v.z * v.y; X[2] = v.z;
        X[3] = v.w * v.x; X[4] = v.w * v.y; X[5] = v.w;
        X[6] = v.x;       X[7] = v.y;       X[8] = 1.0f;
        int idx = 0;
#pragma unroll
        for (int j = 0; j < 9; ++j) {
            float wXj = wt * X[j];
#pragma unroll
            for (int i = j; i < 9; ++i) {
                acc[idx] += X[i] * wXj;
                ++idx;
            }
        }
    }

    // wave (64-lane) shuffle reduction
#pragma unroll
    for (int k = 0; k < 45; ++k) {
        float v = acc[k];
        for (int off = 32; off > 0; off >>= 1)
            v += __shfl_down(v, off, 64);
        acc[k] = v;
    }
    __shared__ float red[4][45];
    int lane = tid & 63, wv = tid >> 6;
    if (lane == 0) {
#pragma unroll
        for (int k = 0; k < 45; ++k) red[wv][k] = acc[k];
    }
    __syncthreads();
    if (tid < 45) {
        double s = (double)red[0][tid] + (double)red[1][tid]
                 + (double)red[2][tid] + (double)red[3][tid];
        atomicAdd(&gram[(size_t)b * 45 + tid], s);
    }
}

// =====================================================================
// Phase 2: faithful float32 LAPACK ssyevd path for 9x9 symmetric:
//   ssytd2('L') -> ssteqr('I') -> apply Q to eigvec column 1 -> normalize
// Replicates branch structure & sign conventions so eigenvector signs
// match numpy's LAPACK. slartg = LAPACK >= 3.10 convention (c >= 0).
// NOTE: ssteqr calls SLARTG(G, F, C, S, R) -- G first! (bug fixed in R1)
// =====================================================================

__device__ __forceinline__ float f_sign(float a, float b) {
    // Fortran SIGN(a,b)
    return (b >= 0.0f) ? fabsf(a) : -fabsf(a);
}

__device__ __forceinline__ float slapy2(float xx, float yy) {
    float xa = fabsf(xx), ya = fabsf(yy);
    float w_ = fmaxf(xa, ya), z_ = fminf(xa, ya);
    if (z_ == 0.0f) return w_;
    float t = z_ / w_;
    return w_ * sqrtf(1.0f + t * t);
}

// LAPACK 3.10+ slartg (fast path; magnitudes here are safely mid-range)
// args: (f, g) in LAPACK's naming; ssteqr passes (G_loopvar, F_loopvar).
__device__ __forceinline__ void slartg(float f, float g, float* cs, float* sn, float* r) {
    if (g == 0.0f) { *cs = 1.0f; *sn = 0.0f; *r = f; }
    else if (f == 0.0f) { *cs = 0.0f; *sn = (g >= 0.0f) ? 1.0f : -1.0f; *r = fabsf(g); }
    else {
        float dd = sqrtf(f * f + g * g);
        *cs = fabsf(f) / dd;
        *r  = f_sign(dd, f);
        *sn = g / (*r);
    }
}

__device__ void slaev2(float a, float b, float c_, float* rt1, float* rt2,
                       float* cs1, float* sn1) {
    float sm = a + c_;
    float df = a - c_;
    float adf = fabsf(df);
    float tb = b + b;
    float ab = fabsf(tb);
    float acmx, acmn;
    if (fabsf(a) > fabsf(c_)) { acmx = a; acmn = c_; } else { acmx = c_; acmn = a; }
    float rt;
    if (adf > ab)      { float t = ab / adf; rt = adf * sqrtf(1.0f + t * t); }
    else if (adf < ab) { float t = adf / ab; rt = ab * sqrtf(1.0f + t * t); }
    else               { rt = ab * sqrtf(2.0f); }
    int sgn1;
    if (sm < 0.0f) {
        *rt1 = 0.5f * (sm - rt); sgn1 = -1;
        *rt2 = (acmx / (*rt1)) * acmn - (b / (*rt1)) * b;
    } else if (sm > 0.0f) {
        *rt1 = 0.5f * (sm + rt); sgn1 = 1;
        *rt2 = (acmx / (*rt1)) * acmn - (b / (*rt1)) * b;
    } else {
        *rt1 = 0.5f * rt; *rt2 = -0.5f * rt; sgn1 = 1;
    }
    float cs; int sgn2;
    if (df >= 0.0f) { cs = df + rt; sgn2 = 1; } else { cs = df - rt; sgn2 = -1; }
    float acs = fabsf(cs);
    if (acs > ab) {
        float ct = -tb / cs;
        *sn1 = 1.0f / sqrtf(1.0f + ct * ct);
        *cs1 = ct * (*sn1);
    } else {
        if (ab == 0.0f) { *cs1 = 1.0f; *sn1 = 0.0f; }
        else {
            float tn = -cs / tb;
            *cs1 = 1.0f / sqrtf(1.0f + tn * tn);
            *sn1 = tn * (*cs1);
        }
    }
    if (sgn1 == sgn2) { float tn = *cs1; *cs1 = -(*sn1); *sn1 = tn; }
}

__global__ __launch_bounds__(64) void eig_kernel(
    const double* __restrict__ gram, float* __restrict__ out)
{
    int b = blockIdx.x * 64 + threadIdx.x;
    if (b >= BATCH) return;
    const int n = 9;

    float A[10][10];     // 1-based, lower triangle valid; reflectors stored below subdiag
    float Z[10][10];     // 1-based, Z[row][col]
    float dd[11], ee[11], tau[10], cw[10], sw[10];

    // ---- load lower triangle ----
    {
        const double* g = gram + (size_t)b * 45;
        int idx = 0;
        for (int j = 1; j <= n; ++j)
            for (int i = j; i <= n; ++i) {
                A[i][j] = (float)g[idx]; ++idx;
            }
    }

    // ---- ssytd2 ('L') ----
    for (int i = 1; i <= n - 1; ++i) {
        float alpha = A[i + 1][i];
        float ssq = 0.0f;
        for (int k = i + 2; k <= n; ++k) ssq += A[k][i] * A[k][i];
        float xnorm = sqrtf(ssq);
        float taui;
        if (xnorm == 0.0f) {
            taui = 0.0f;
            ee[i] = alpha;
        } else {
            float beta = -f_sign(slapy2(alpha, xnorm), alpha);
            taui = (beta - alpha) / beta;
            float sc = 1.0f / (alpha - beta);
            for (int k = i + 2; k <= n; ++k) A[k][i] *= sc;
            ee[i] = beta;
        }
        if (taui != 0.0f) {
            float v[10], wv[10];
            v[i + 1] = 1.0f;
            for (int k = i + 2; k <= n; ++k) v[k] = A[k][i];
            // w = taui * A(i+1:n,i+1:n) * v  (symmetric, lower stored)
            for (int r2 = i + 1; r2 <= n; ++r2) {
                float s2 = 0.0f;
                for (int c2 = i + 1; c2 <= n; ++c2) {
                    float aval = (r2 >= c2) ? A[r2][c2] : A[c2][r2];
                    s2 += aval * v[c2];
                }
                wv[r2] = taui * s2;
            }
            float dot = 0.0f;
            for (int k = i + 1; k <= n; ++k) dot += wv[k] * v[k];
            float alpha2 = -0.5f * taui * dot;
            for (int k = i + 1; k <= n; ++k) wv[k] += alpha2 * v[k];
            // rank-2 update (lower)
            for (int c2 = i + 1; c2 <= n; ++c2)
                for (int r2 = c2; r2 <= n; ++r2)
                    A[r2][c2] -= v[r2] * wv[c2] + wv[r2] * v[c2];
        }
        dd[i] = A[i][i];
        tau[i] = taui;
    }
    dd[n] = A[n][n];

    // ---- Z = I ----
    for (int r2 = 1; r2 <= n; ++r2)
        for (int c2 = 1; c2 <= n; ++c2)
            Z[r2][c2] = (r2 == c2) ? 1.0f : 0.0f;

    // ---- ssteqr ('I') : faithful transcription ----
    const float eps    = 5.9604645e-8f;       // 2^-24
    const float eps2   = eps * eps;
    const float safmin = 1.17549435e-38f;
    const float safmax = 1.0f / 1.17549435e-38f;
    const float ssfmax = sqrtf(safmax) / 3.0f;
    const float ssfmin = sqrtf(safmin) / eps2;

    int nmaxit = n * 30, jtot = 0;
    int l1 = 1, nm1 = n - 1;
    int l, m, lsv, lend, lendsv, iscale;
    float anorm, p, g, r, c, s, f, btmp, rt1, rt2, tst, mul;

L10:
    if (l1 > n) goto L160;
    if (l1 > 1) ee[l1 - 1] = 0.0f;
    if (l1 <= nm1) {
        for (m = l1; m <= nm1; ++m) {
            tst = fabsf(ee[m]);
            if (tst == 0.0f) goto L30;
            if (tst <= (sqrtf(fabsf(dd[m])) * sqrtf(fabsf(dd[m + 1]))) * eps) {
                ee[m] = 0.0f;
                goto L30;
            }
        }
    }
    m = n;
L30:
    l = l1; lsv = l; lend = m; lendsv = lend; l1 = m + 1;
    if (lend == l) goto L10;

    anorm = 0.0f;
    for (int k = l; k <= lend; ++k) anorm = fmaxf(anorm, fabsf(dd[k]));
    for (int k = l; k <= lend - 1; ++k) anorm = fmaxf(anorm, fabsf(ee[k]));
    iscale = 0;
    if (anorm == 0.0f) goto L10;
    if (anorm > ssfmax) {
        iscale = 1; mul = ssfmax / anorm;
        for (int k = l; k <= lend; ++k) dd[k] *= mul;
        for (int k = l; k <= lend - 1; ++k) ee[k] *= mul;
    } else if (anorm < ssfmin) {
        iscale = 2; mul = ssfmin / anorm;
        for (int k = l; k <= lend; ++k) dd[k] *= mul;
        for (int k = l; k <= lend - 1; ++k) ee[k] *= mul;
    }

    if (fabsf(dd[lend]) < fabsf(dd[l])) { lend = lsv; l = lendsv; }

    if (lend > l) {
        // ---------- QL iteration ----------
L40:
        if (l != lend) {
            for (m = l; m <= lend - 1; ++m) {
                tst = fabsf(ee[m]); tst = tst * tst;
                if (tst <= (eps2 * fabsf(dd[m])) * fabsf(dd[m + 1]) + safmin) goto L60;
            }
        }
        m = lend;
L60:
        if (m < lend) ee[m] = 0.0f;
        p = dd[l];
        if (m == l) goto L80;
        if (m == l + 1) {
            slaev2(dd[l], ee[l], dd[l + 1], &rt1, &rt2, &c, &s);
            cw[l] = c; sw[l] = s;
            for (int row = 1; row <= n; ++row) {
                float temp = Z[row][l + 1];
                Z[row][l + 1] = c * temp - s * Z[row][l];
                Z[row][l]     = s * temp + c * Z[row][l];
            }
            dd[l] = rt1; dd[l + 1] = rt2; ee[l] = 0.0f;
            l += 2;
            if (l <= lend) goto L40;
            goto L140;
        }
        if (jtot == nmaxit) goto L140;
        ++jtot;
        g = (dd[l + 1] - p) / (2.0f * ee[l]);
        r = slapy2(g, 1.0f);
        g = dd[m] - p + ee[l] / (g + f_sign(r, g));
        s = 1.0f; c = 1.0f; p = 0.0f;
        for (int i = m - 1; i >= l; --i) {
            f = s * ee[i]; btmp = c * ee[i];
            slartg(g, f, &c, &s, &r);        // LAPACK: CALL SLARTG(G, F, C, S, R)
            if (i != m - 1) ee[i + 1] = r;
            g = dd[i + 1] - p;
            r = (dd[i] - g) * s + 2.0f * c * btmp;
            p = s * r;
            dd[i + 1] = g + p;
            g = c * r - btmp;
            cw[i] = c; sw[i] = -s;
        }
        for (int j = m - 1; j >= l; --j) {
            float ct = cw[j], st = sw[j];
            if (ct != 1.0f || st != 0.0f) {
                for (int row = 1; row <= n; ++row) {
                    float temp = Z[row][j + 1];
                    Z[row][j + 1] = ct * temp - st * Z[row][j];
                    Z[row][j]     = st * temp + ct * Z[row][j];
                }
            }
        }
        dd[l] = dd[l] - p;
        ee[l] = g;
        goto L40;
L80:
        dd[l] = p;
        l = l + 1;
        if (l <= lend) goto L40;
        goto L140;
    } else {
        // ---------- QR iteration ----------
L90:
        if (l != lend) {
            for (m = l; m >= lend + 1; --m) {
                tst = fabsf(ee[m - 1]); tst = tst * tst;
                if (tst <= (eps2 * fabsf(dd[m])) * fabsf(dd[m - 1]) + safmin) goto L110;
            }
        }
        m = lend;
L110:
        if (m > lend) ee[m - 1] = 0.0f;
        p = dd[l];
        if (m == l) goto L130;
        if (m == l - 1) {
            slaev2(dd[l - 1], ee[l - 1], dd[l], &rt1, &rt2, &c, &s);
            cw[m] = c; sw[m] = s;
            for (int row = 1; row <= n; ++row) {
                float temp = Z[row][l];
                Z[row][l]     = c * temp - s * Z[row][l - 1];
                Z[row][l - 1] = s * temp + c * Z[row][l - 1];
            }
            dd[l - 1] = rt1; dd[l] = rt2; ee[l - 1] = 0.0f;
            l -= 2;
            if (l >= lend) goto L90;
            goto L140;
        }
        if (jtot == nmaxit) goto L140;
        ++jtot;
        g = (dd[l - 1] - p) / (2.0f * ee[l - 1]);
        r = slapy2(g, 1.0f);
        g = dd[m] - p + ee[l - 1] / (g + f_sign(r, g));
        s = 1.0f; c = 1.0f; p = 0.0f;
        for (int i = m; i <= l - 1; ++i) {
            f = s * ee[i]; btmp = c * ee[i];
            slartg(g, f, &c, &s, &r);        // LAPACK: CALL SLARTG(G, F, C, S, R)
            if (i != m) ee[i - 1] = r;
            g = dd[i] - p;
            r = (dd[i + 1] - g) * s + 2.0f * c * btmp;
            p = s * r;
            dd[i] = g + p;
            g = c * r - btmp;
            cw[i] = c; sw[i] = s;
        }
        for (int j = m; j <= l - 1; ++j) {
            float ct = cw[j], st = sw[j];
            if (ct != 1.0f || st != 0.0f) {
                for (int row = 1; row <= n; ++row) {
                    float temp = Z[row][j + 1];
                    Z[row][j + 1] = ct * temp - st * Z[row][j];
                    Z[row][j]     = st * temp + ct * Z[row][j];
                }
            }
        }
        dd[l] = dd[l] - p;
        ee[l - 1] = g;
        goto L90;
L130:
        dd[l] = p;
        l = l - 1;
        if (l >= lend) goto L90;
        goto L140;
    }

L140:
    if (iscale == 1) {
        mul = anorm / ssfmax;
        for (int k = lsv; k <= lendsv; ++k) dd[k] *= mul;
        for (int k = lsv; k <= lendsv - 1; ++k) ee[k] *= mul;
    } else if (iscale == 2) {
        mul = anorm / ssfmin;
        for (int k = lsv; k <= lendsv; ++k) dd[k] *= mul;
        for (int k = lsv; k <= lendsv - 1; ++k) ee[k] *= mul;
    }
    if (jtot < nmaxit) goto L10;
    goto L160;   // non-convergence: proceed with what we have

L160:
    // selection sort, ascending (matches ssteqr exactly, incl. strict '<')
    for (int ii = 2; ii <= n; ++ii) {
        int i = ii - 1, k = i;
        p = dd[i];
        for (int j = ii; j <= n; ++j)
            if (dd[j] < p) { k = j; p = dd[j]; }
        if (k != i) {
            dd[k] = dd[i]; dd[i] = p;
            for (int row = 1; row <= n; ++row) {
                float t = Z[row][i]; Z[row][i] = Z[row][k]; Z[row][k] = t;
            }
        }
    }

    // ---- apply Q (sormtr 'L','L','N'): zv = H(1)...H(n-1) * Z(:,1) ----
    {
        float zv[10];
        for (int row = 1; row <= n; ++row) zv[row] = Z[row][1];
        for (int i = n - 1; i >= 1; --i) {
            if (tau[i] != 0.0f) {
                float dotp = zv[i + 1];
                for (int k = i + 2; k <= n; ++k) dotp += A[k][i] * zv[k];
                float t = tau[i] * dotp;
                zv[i + 1] -= t;
                for (int k = i + 2; k <= n; ++k) zv[k] -= t * A[k][i];
            }
        }
        float nrm = 0.0f;
        for (int row = 1; row <= n; ++row) nrm += zv[row] * zv[row];
        nrm = sqrtf(nrm);
        for (int row = 1; row <= n; ++row)
            out[(size_t)b * 9 + (row - 1)] = zv[row] / nrm;
    }
}

extern "C" void kernel_launch(void* const* d_in, const int* in_sizes, int n_in,
                              void* d_out, int out_size, void* d_ws, size_t ws_size,
                              hipStream_t stream) {
    const float4* x = (const float4*)d_in[0];   // (256,1,20000,4) f32
    const float*  w = (const float*)d_in[1];    // (256,20000) f32
    float* out = (float*)d_out;                 // (256,9) f32
    double* gram = (double*)d_ws;               // 256*45 doubles

    hipMemsetAsync(gram, 0, (size_t)BATCH * 45 * sizeof(double), stream);
    gram_kernel<<<dim3(BATCH, NCHUNK), dim3(256), 0, stream>>>(x, w, gram);
    eig_kernel<<<dim3(BATCH / 64), dim3(64), 0, stream>>>(gram, out);
}

// Round 3
// 206.269 us; speedup vs baseline: 2.3429x; 2.3429x over previous
//
#include <hip/hip_runtime.h>
#include <math.h>

#define BATCH 256
#define NPTS  20000
#define NCHUNK 4
#define PERCH (NPTS / NCHUNK)   // 5000

// =====================================================================
// Phase 1: weighted 9x9 Gram accumulation (lower triangle, 45 entries).
// Writes per-(batch,chunk) partial sums (double) -- no atomics, no memset.
// NCHUNK=4: 20 main-loop iters/thread amortizes the 270-shuffle tail.
// ws use: 256*4*45*8 = 368640 B.
// =====================================================================
__global__ __launch_bounds__(256) void gram_kernel(
    const float4* __restrict__ x, const float* __restrict__ w,
    double* __restrict__ partial)
{
    int b = blockIdx.x;
    int chunk = blockIdx.y;
    int tid = threadIdx.x;

    float acc[45];
#pragma unroll
    for (int k = 0; k < 45; ++k) acc[k] = 0.0f;

    const float4* xb = x + (size_t)b * NPTS;
    const float*  wb = w + (size_t)b * NPTS;
    int base = chunk * PERCH;
    for (int n = base + tid; n < base + PERCH; n += 256) {
        float4 v = xb[n];
        float wt = wb[n];
        float X[9];
        X[0] = v.z * v.x; X[1] = v.z * v.y; X[2] = v.z;
        X[3] = v.w * v.x; X[4] = v.w * v.y; X[5] = v.w;
        X[6] = v.x;       X[7] = v.y;       X[8] = 1.0f;
        int idx = 0;
#pragma unroll
        for (int j = 0; j < 9; ++j) {
            float wXj = wt * X[j];
#pragma unroll
            for (int i = j; i < 9; ++i) {
                acc[idx] += X[i] * wXj;
                ++idx;
            }
        }
    }

    // wave (64-lane) shuffle reduction
#pragma unroll
    for (int k = 0; k < 45; ++k) {
        float v = acc[k];
        for (int off = 32; off > 0; off >>= 1)
            v += __shfl_down(v, off, 64);
        acc[k] = v;
    }
    __shared__ float red[4][45];
    int lane = tid & 63, wv = tid >> 6;
    if (lane == 0) {
#pragma unroll
        for (int k = 0; k < 45; ++k) red[wv][k] = acc[k];
    }
    __syncthreads();
    if (tid < 45) {
        double s = (double)red[0][tid] + (double)red[1][tid]
                 + (double)red[2][tid] + (double)red[3][tid];
        partial[((size_t)b * NCHUNK + chunk) * 45 + tid] = s;
    }
}

// =====================================================================
// Phase 2: faithful float32 LAPACK ssyevd path for 9x9 symmetric.
// R3 restructure: ONE MATRIX PER BLOCK (1 wave). All 64 lanes redundantly
// run the scalar control flow on shared LDS state (wave-uniform branches,
// zero divergence, no scratch spills). Element-wise loops parallelized
// across lanes with identical per-element fp32 arithmetic. Single wave =>
// lockstep + in-order LDS => no barriers needed.
// =====================================================================

__device__ __forceinline__ float f_sign(float a, float b) {
    return (b >= 0.0f) ? fabsf(a) : -fabsf(a);
}

__device__ __forceinline__ float slapy2(float xx, float yy) {
    float xa = fabsf(xx), ya = fabsf(yy);
    float w_ = fmaxf(xa, ya), z_ = fminf(xa, ya);
    if (z_ == 0.0f) return w_;
    float t = z_ / w_;
    return w_ * sqrtf(1.0f + t * t);
}

// LAPACK 3.10+ slartg; ssteqr passes (G, F) -- G first.
__device__ __forceinline__ void slartg(float f, float g, float* cs, float* sn, float* r) {
    if (g == 0.0f) { *cs = 1.0f; *sn = 0.0f; *r = f; }
    else if (f == 0.0f) { *cs = 0.0f; *sn = (g >= 0.0f) ? 1.0f : -1.0f; *r = fabsf(g); }
    else {
        float dd = sqrtf(f * f + g * g);
        *cs = fabsf(f) / dd;
        *r  = f_sign(dd, f);
        *sn = g / (*r);
    }
}

__device__ void slaev2(float a, float b, float c_, float* rt1, float* rt2,
                       float* cs1, float* sn1) {
    float sm = a + c_;
    float df = a - c_;
    float adf = fabsf(df);
    float tb = b + b;
    float ab = fabsf(tb);
    float acmx, acmn;
    if (fabsf(a) > fabsf(c_)) { acmx = a; acmn = c_; } else { acmx = c_; acmn = a; }
    float rt;
    if (adf > ab)      { float t = ab / adf; rt = adf * sqrtf(1.0f + t * t); }
    else if (adf < ab) { float t = adf / ab; rt = ab * sqrtf(1.0f + t * t); }
    else               { rt = ab * sqrtf(2.0f); }
    int sgn1;
    if (sm < 0.0f) {
        *rt1 = 0.5f * (sm - rt); sgn1 = -1;
        *rt2 = (acmx / (*rt1)) * acmn - (b / (*rt1)) * b;
    } else if (sm > 0.0f) {
        *rt1 = 0.5f * (sm + rt); sgn1 = 1;
        *rt2 = (acmx / (*rt1)) * acmn - (b / (*rt1)) * b;
    } else {
        *rt1 = 0.5f * rt; *rt2 = -0.5f * rt; sgn1 = 1;
    }
    float cs; int sgn2;
    if (df >= 0.0f) { cs = df + rt; sgn2 = 1; } else { cs = df - rt; sgn2 = -1; }
    float acs = fabsf(cs);
    if (acs > ab) {
        float ct = -tb / cs;
        *sn1 = 1.0f / sqrtf(1.0f + ct * ct);
        *cs1 = ct * (*sn1);
    } else {
        if (ab == 0.0f) { *cs1 = 1.0f; *sn1 = 0.0f; }
        else {
            float tn = -cs / tb;
            *cs1 = 1.0f / sqrtf(1.0f + tn * tn);
            *sn1 = tn * (*cs1);
        }
    }
    if (sgn1 == sgn2) { float tn = *cs1; *cs1 = -(*sn1); *sn1 = tn; }
}

__global__ __launch_bounds__(64) void eig_kernel(
    const double* __restrict__ partial, float* __restrict__ out)
{
    const int n = 9;
    int b = blockIdx.x;
    int lane = threadIdx.x;

    __shared__ float A[10][10];    // 1-based; lower triangle + reflectors
    __shared__ float Z[10][10];    // 1-based, Z[row][col]
    __shared__ float dd[11], ee[11], tau[10], cw[10], sw[10], wv[10], zv[10];

    // ---- load lower triangle: lanes 0..44, sum 4 chunk partials in order ----
    if (lane < 45) {
        const double* p = partial + (size_t)b * (45 * NCHUNK) + lane;
        double s = ((p[0] + p[45]) + p[90]) + p[135];
        int idx = lane, j = 1;
        while (idx >= 10 - j) { idx -= (10 - j); ++j; }
        int i = j + idx;
        A[i][j] = (float)s;
    }

    // ---- Z = I ----
    for (int e = lane; e < 100; e += 64) {
        int r0 = e / 10, c0 = e % 10;
        Z[r0][c0] = (r0 == c0) ? 1.0f : 0.0f;
    }

    // ---- ssytd2 ('L') ----
    for (int i = 1; i <= n - 1; ++i) {
        float alpha = A[i + 1][i];
        float ssq = 0.0f;
        for (int k = i + 2; k <= n; ++k) ssq += A[k][i] * A[k][i];
        float xnorm = sqrtf(ssq);
        float taui;
        if (xnorm == 0.0f) {
            taui = 0.0f;
            if (lane == 0) ee[i] = alpha;
        } else {
            float beta = -f_sign(slapy2(alpha, xnorm), alpha);
            taui = (beta - alpha) / beta;
            float sc = 1.0f / (alpha - beta);
            if (lane < 8 - i) {                 // k = i+2 .. 9
                int k = i + 2 + lane;
                A[k][i] *= sc;
            }
            if (lane == 0) ee[i] = beta;
        }
        if (taui != 0.0f) {
            // wv = taui * A_sub * v   (v[i+1]=1, v[k]=A[k][i]); rows parallel,
            // inner sum c2 ascending (same order as scalar version)
            if (lane < 9 - i) {
                int r2 = i + 1 + lane;
                float s2 = 0.0f;
                for (int c2 = i + 1; c2 <= n; ++c2) {
                    float aval = (r2 >= c2) ? A[r2][c2] : A[c2][r2];
                    float vc = (c2 == i + 1) ? 1.0f : A[c2][i];
                    s2 += aval * vc;
                }
                wv[r2] = taui * s2;
            }
            float dot = 0.0f;
            for (int k = i + 1; k <= n; ++k) {
                float vk = (k == i + 1) ? 1.0f : A[k][i];
                dot += wv[k] * vk;
            }
            float alpha2 = -0.5f * taui * dot;
            if (lane < 9 - i) {
                int k = i + 1 + lane;
                float vk = (k == i + 1) ? 1.0f : A[k][i];
                wv[k] += alpha2 * vk;
            }
            // rank-2 lower update of A(i+1:9, i+1:9), one entry per lane
            int kk = 9 - i;
            int cnt = kk * (kk + 1) / 2;
            if (lane < cnt) {
                int idx = lane, cc = 0;
                while (idx >= kk - cc) { idx -= (kk - cc); ++cc; }
                int c2 = i + 1 + cc;
                int r2 = c2 + idx;
                float vr = (r2 == i + 1) ? 1.0f : A[r2][i];
                float vc = (c2 == i + 1) ? 1.0f : A[c2][i];
                A[r2][c2] -= vr * wv[c2] + wv[r2] * vc;
            }
        }
        if (lane == 0) { dd[i] = A[i][i]; tau[i] = taui; }
    }
    if (lane == 0) dd[n] = A[n][n];

    // ---- ssteqr ('I') ----
    const float eps    = 5.9604645e-8f;
    const float eps2   = eps * eps;
    const float safmin = 1.17549435e-38f;
    const float safmax = 1.0f / 1.17549435e-38f;
    const float ssfmax = sqrtf(safmax) / 3.0f;
    const float ssfmin = sqrtf(safmin) / eps2;

    int nmaxit = n * 30, jtot = 0;
    int l1 = 1, nm1 = n - 1;
    int l, m, lsv, lend, lendsv, iscale;
    float anorm, p, g, r, c, s, f, btmp, rt1, rt2, tst, mul;

L10:
    if (l1 > n) goto L160;
    if (l1 > 1) { if (lane == 0) ee[l1 - 1] = 0.0f; }
    if (l1 <= nm1) {
        for (m = l1; m <= nm1; ++m) {
            tst = fabsf(ee[m]);
            if (tst == 0.0f) goto L30;
            if (tst <= (sqrtf(fabsf(dd[m])) * sqrtf(fabsf(dd[m + 1]))) * eps) {
                if (lane == 0) ee[m] = 0.0f;
                goto L30;
            }
        }
    }
    m = n;
L30:
    l = l1; lsv = l; lend = m; lendsv = lend; l1 = m + 1;
    if (lend == l) goto L10;

    anorm = 0.0f;
    for (int k = l; k <= lend; ++k) anorm = fmaxf(anorm, fabsf(dd[k]));
    for (int k = l; k <= lend - 1; ++k) anorm = fmaxf(anorm, fabsf(ee[k]));
    iscale = 0;
    if (anorm == 0.0f) goto L10;
    if (anorm > ssfmax) {
        iscale = 1; mul = ssfmax / anorm;
        if (lane <= lend - l) dd[l + lane] *= mul;
        if (lane <  lend - l) ee[l + lane] *= mul;
    } else if (anorm < ssfmin) {
        iscale = 2; mul = ssfmin / anorm;
        if (lane <= lend - l) dd[l + lane] *= mul;
        if (lane <  lend - l) ee[l + lane] *= mul;
    }

    if (fabsf(dd[lend]) < fabsf(dd[l])) { lend = lsv; l = lendsv; }

    if (lend > l) {
        // ---------- QL ----------
L40:
        if (l != lend) {
            for (m = l; m <= lend - 1; ++m) {
                tst = fabsf(ee[m]); tst = tst * tst;
                if (tst <= (eps2 * fabsf(dd[m])) * fabsf(dd[m + 1]) + safmin) goto L60;
            }
        }
        m = lend;
L60:
        if (m < lend) { if (lane == 0) ee[m] = 0.0f; }
        p = dd[l];
        if (m == l) goto L80;
        if (m == l + 1) {
            slaev2(dd[l], ee[l], dd[l + 1], &rt1, &rt2, &c, &s);
            if (lane < 9) {
                int row = lane + 1;
                float temp = Z[row][l + 1];
                Z[row][l + 1] = c * temp - s * Z[row][l];
                Z[row][l]     = s * temp + c * Z[row][l];
            }
            if (lane == 0) { dd[l] = rt1; dd[l + 1] = rt2; ee[l] = 0.0f; }
            l += 2;
            if (l <= lend) goto L40;
            goto L140;
        }
        if (jtot == nmaxit) goto L140;
        ++jtot;
        g = (dd[l + 1] - p) / (2.0f * ee[l]);
        r = slapy2(g, 1.0f);
        g = dd[m] - p + ee[l] / (g + f_sign(r, g));
        s = 1.0f; c = 1.0f; p = 0.0f;
        for (int i = m - 1; i >= l; --i) {
            f = s * ee[i]; btmp = c * ee[i];
            slartg(g, f, &c, &s, &r);
            if (i != m - 1) { if (lane == 0) ee[i + 1] = r; }
            g = dd[i + 1] - p;
            r = (dd[i] - g) * s + 2.0f * c * btmp;
            p = s * r;
            if (lane == 0) dd[i + 1] = g + p;
            g = c * r - btmp;
            if (lane == 0) { cw[i] = c; sw[i] = -s; }
        }
        for (int j = m - 1; j >= l; --j) {
            float ct = cw[j], st = sw[j];
            if (ct != 1.0f || st != 0.0f) {
                if (lane < 9) {
                    int row = lane + 1;
                    float temp = Z[row][j + 1];
                    Z[row][j + 1] = ct * temp - st * Z[row][j];
                    Z[row][j]     = st * temp + ct * Z[row][j];
                }
            }
        }
        if (lane == 0) { dd[l] -= p; ee[l] = g; }
        goto L40;
L80:
        if (lane == 0) dd[l] = p;
        l = l + 1;
        if (l <= lend) goto L40;
        goto L140;
    } else {
        // ---------- QR ----------
L90:
        if (l != lend) {
            for (m = l; m >= lend + 1; --m) {
                tst = fabsf(ee[m - 1]); tst = tst * tst;
                if (tst <= (eps2 * fabsf(dd[m])) * fabsf(dd[m - 1]) + safmin) goto L110;
            }
        }
        m = lend;
L110:
        if (m > lend) { if (lane == 0) ee[m - 1] = 0.0f; }
        p = dd[l];
        if (m == l) goto L130;
        if (m == l - 1) {
            slaev2(dd[l - 1], ee[l - 1], dd[l], &rt1, &rt2, &c, &s);
            if (lane < 9) {
                int row = lane + 1;
                float temp = Z[row][l];
                Z[row][l]     = c * temp - s * Z[row][l - 1];
                Z[row][l - 1] = s * temp + c * Z[row][l - 1];
            }
            if (lane == 0) { dd[l - 1] = rt1; dd[l] = rt2; ee[l - 1] = 0.0f; }
            l -= 2;
            if (l >= lend) goto L90;
            goto L140;
        }
        if (jtot == nmaxit) goto L140;
        ++jtot;
        g = (dd[l - 1] - p) / (2.0f * ee[l - 1]);
        r = slapy2(g, 1.0f);
        g = dd[m] - p + ee[l - 1] / (g + f_sign(r, g));
        s = 1.0f; c = 1.0f; p = 0.0f;
        for (int i = m; i <= l - 1; ++i) {
            f = s * ee[i]; btmp = c * ee[i];
            slartg(g, f, &c, &s, &r);
            if (i != m) { if (lane == 0) ee[i - 1] = r; }
            g = dd[i] - p;
            r = (dd[i + 1] - g) * s + 2.0f * c * btmp;
            p = s * r;
            if (lane == 0) dd[i] = g + p;
            g = c * r - btmp;
            if (lane == 0) { cw[i] = c; sw[i] = s; }
        }
        for (int j = m; j <= l - 1; ++j) {
            float ct = cw[j], st = sw[j];
            if (ct != 1.0f || st != 0.0f) {
                if (lane < 9) {
                    int row = lane + 1;
                    float temp = Z[row][j + 1];
                    Z[row][j + 1] = ct * temp - st * Z[row][j];
                    Z[row][j]     = st * temp + ct * Z[row][j];
                }
            }
        }
        if (lane == 0) { dd[l] -= p; ee[l - 1] = g; }
        goto L90;
L130:
        if (lane == 0) dd[l] = p;
        l = l - 1;
        if (l >= lend) goto L90;
        goto L140;
    }

L140:
    if (iscale == 1) {
        mul = anorm / ssfmax;
        if (lane <= lendsv - lsv) dd[lsv + lane] *= mul;
        if (lane <  lendsv - lsv) ee[lsv + lane] *= mul;
    } else if (iscale == 2) {
        mul = anorm / ssfmin;
        if (lane <= lendsv - lsv) dd[lsv + lane] *= mul;
        if (lane <  lendsv - lsv) ee[lsv + lane] *= mul;
    }
    if (jtot < nmaxit) goto L10;
    goto L160;

L160:
    // selection sort ascending (strict '<', matches ssteqr)
    for (int ii = 2; ii <= n; ++ii) {
        int i = ii - 1, k = i;
        p = dd[i];
        for (int j = ii; j <= n; ++j)
            if (dd[j] < p) { k = j; p = dd[j]; }
        if (k != i) {
            if (lane == 0) { dd[k] = dd[i]; dd[i] = p; }
            if (lane < 9) {
                int row = lane + 1;
                float t = Z[row][i]; Z[row][i] = Z[row][k]; Z[row][k] = t;
            }
        }
    }

    // ---- apply Q (sormtr 'L','L','N') to Z(:,1), then normalize ----
    if (lane < 9) zv[lane + 1] = Z[lane + 1][1];
    for (int i2 = n - 1; i2 >= 1; --i2) {
        float ti = tau[i2];
        if (ti != 0.0f) {
            float dotp = zv[i2 + 1];
            for (int k = i2 + 2; k <= n; ++k) dotp += A[k][i2] * zv[k];
            float t = ti * dotp;
            if (lane < 9 - i2) {
                int k = i2 + 1 + lane;
                float upd = (k == i2 + 1) ? t : t * A[k][i2];
                zv[k] -= upd;
            }
        }
    }
    {
        float nrm = 0.0f;
        for (int row = 1; row <= n; ++row) nrm += zv[row] * zv[row];
        nrm = sqrtf(nrm);
        if (lane < 9) out[(size_t)b * 9 + lane] = zv[lane + 1] / nrm;
    }
}

extern "C" void kernel_launch(void* const* d_in, const int* in_sizes, int n_in,
                              void* d_out, int out_size, void* d_ws, size_t ws_size,
                              hipStream_t stream) {
    const float4* x = (const float4*)d_in[0];   // (256,1,20000,4) f32
    const float*  w = (const float*)d_in[1];    // (256,20000) f32
    float* out = (float*)d_out;                 // (256,9) f32
    double* partial = (double*)d_ws;            // 256*4*45 doubles = 368640 B

    gram_kernel<<<dim3(BATCH, NCHUNK), dim3(256), 0, stream>>>(x, w, partial);
    eig_kernel<<<dim3(BATCH), dim3(64), 0, stream>>>(partial, out);
}

// Round 4
// 193.221 us; speedup vs baseline: 2.5011x; 1.0675x over previous
//
#include <hip/hip_runtime.h>
#include <math.h>

#define BATCH 256
#define NPTS  20000
#define NCHUNK 4
#define PERCH (NPTS / NCHUNK)   // 5000

// =====================================================================
// Phase 1: weighted 9x9 Gram accumulation (lower triangle, 45 entries).
// UNCHANGED from R3 (single-variable experiment: this round is eig-only).
// =====================================================================
__global__ __launch_bounds__(256) void gram_kernel(
    const float4* __restrict__ x, const float* __restrict__ w,
    double* __restrict__ partial)
{
    int b = blockIdx.x;
    int chunk = blockIdx.y;
    int tid = threadIdx.x;

    float acc[45];
#pragma unroll
    for (int k = 0; k < 45; ++k) acc[k] = 0.0f;

    const float4* xb = x + (size_t)b * NPTS;
    const float*  wb = w + (size_t)b * NPTS;
    int base = chunk * PERCH;
    for (int n = base + tid; n < base + PERCH; n += 256) {
        float4 v = xb[n];
        float wt = wb[n];
        float X[9];
        X[0] = v.z * v.x; X[1] = v.z * v.y; X[2] = v.z;
        X[3] = v.w * v.x; X[4] = v.w * v.y; X[5] = v.w;
        X[6] = v.x;       X[7] = v.y;       X[8] = 1.0f;
        int idx = 0;
#pragma unroll
        for (int j = 0; j < 9; ++j) {
            float wXj = wt * X[j];
#pragma unroll
            for (int i = j; i < 9; ++i) {
                acc[idx] += X[i] * wXj;
                ++idx;
            }
        }
    }

#pragma unroll
    for (int k = 0; k < 45; ++k) {
        float v = acc[k];
        for (int off = 32; off > 0; off >>= 1)
            v += __shfl_down(v, off, 64);
        acc[k] = v;
    }
    __shared__ float red[4][45];
    int lane = tid & 63, wv = tid >> 6;
    if (lane == 0) {
#pragma unroll
        for (int k = 0; k < 45; ++k) red[wv][k] = acc[k];
    }
    __syncthreads();
    if (tid < 45) {
        double s = (double)red[0][tid] + (double)red[1][tid]
                 + (double)red[2][tid] + (double)red[3][tid];
        partial[((size_t)b * NCHUNK + chunk) * 45 + tid] = s;
    }
}

// =====================================================================
// Phase 2: faithful float32 LAPACK ssyevd path for 9x9 symmetric.
// R4: ssteqr state registerized. dd/ee/cw/sw are lane-distributed VGPRs
// (lane i holds element i; reads via v_readlane with uniform index,
// writes via cndmask). Z rows live in per-lane registers (lane r = row r)
// and sweeps are applied as identity-padded fully-unrolled passes.
// ssytd2 / sort / epilogue unchanged (LDS). 1 wave/block, wave-uniform
// control flow, no barriers needed.
// =====================================================================

__device__ __forceinline__ float f_sign(float a, float b) {
    return (b >= 0.0f) ? fabsf(a) : -fabsf(a);
}

__device__ __forceinline__ float slapy2(float xx, float yy) {
    float xa = fabsf(xx), ya = fabsf(yy);
    float w_ = fmaxf(xa, ya), z_ = fminf(xa, ya);
    if (z_ == 0.0f) return w_;
    float t = z_ / w_;
    return w_ * sqrtf(1.0f + t * t);
}

// lane-broadcast read of a lane-distributed register value (uniform idx)
__device__ __forceinline__ float rdl(float v, int i) {
    return __int_as_float(__builtin_amdgcn_readlane(__float_as_int(v), i));
}

// LAPACK 3.10+ slartg; ssteqr passes (G, F) -- G first.
__device__ __forceinline__ void slartg(float f, float g, float* cs, float* sn, float* r) {
    if (g == 0.0f) { *cs = 1.0f; *sn = 0.0f; *r = f; }
    else if (f == 0.0f) { *cs = 0.0f; *sn = (g >= 0.0f) ? 1.0f : -1.0f; *r = fabsf(g); }
    else {
        float dd2 = sqrtf(f * f + g * g);
        *cs = fabsf(f) / dd2;
        *r  = f_sign(dd2, f);
        *sn = g / (*r);
    }
}

__device__ void slaev2(float a, float b, float c_, float* rt1, float* rt2,
                       float* cs1, float* sn1) {
    float sm = a + c_;
    float df = a - c_;
    float adf = fabsf(df);
    float tb = b + b;
    float ab = fabsf(tb);
    float acmx, acmn;
    if (fabsf(a) > fabsf(c_)) { acmx = a; acmn = c_; } else { acmx = c_; acmn = a; }
    float rt;
    if (adf > ab)      { float t = ab / adf; rt = adf * sqrtf(1.0f + t * t); }
    else if (adf < ab) { float t = adf / ab; rt = ab * sqrtf(1.0f + t * t); }
    else               { rt = ab * sqrtf(2.0f); }
    int sgn1;
    if (sm < 0.0f) {
        *rt1 = 0.5f * (sm - rt); sgn1 = -1;
        *rt2 = (acmx / (*rt1)) * acmn - (b / (*rt1)) * b;
    } else if (sm > 0.0f) {
        *rt1 = 0.5f * (sm + rt); sgn1 = 1;
        *rt2 = (acmx / (*rt1)) * acmn - (b / (*rt1)) * b;
    } else {
        *rt1 = 0.5f * rt; *rt2 = -0.5f * rt; sgn1 = 1;
    }
    float cs; int sgn2;
    if (df >= 0.0f) { cs = df + rt; sgn2 = 1; } else { cs = df - rt; sgn2 = -1; }
    float acs = fabsf(cs);
    if (acs > ab) {
        float ct = -tb / cs;
        *sn1 = 1.0f / sqrtf(1.0f + ct * ct);
        *cs1 = ct * (*sn1);
    } else {
        if (ab == 0.0f) { *cs1 = 1.0f; *sn1 = 0.0f; }
        else {
            float tn = -cs / tb;
            *cs1 = 1.0f / sqrtf(1.0f + tn * tn);
            *sn1 = tn * (*cs1);
        }
    }
    if (sgn1 == sgn2) { float tn = *cs1; *cs1 = -(*sn1); *sn1 = tn; }
}

// identity-padded sweep applies (exact no-ops where c=1,s=0)
#define APPLY_QL() do { \
    _Pragma("unroll") \
    for (int jz = 8; jz >= 1; --jz) { \
        float cj = rdl(r_cw, jz), sj = rdl(r_sw, jz); \
        float tmpz = zz[jz + 1]; \
        zz[jz + 1] = cj * tmpz - sj * zz[jz]; \
        zz[jz]     = sj * tmpz + cj * zz[jz]; \
    } } while (0)

#define APPLY_QR() do { \
    _Pragma("unroll") \
    for (int jz = 1; jz <= 8; ++jz) { \
        float cj = rdl(r_cw, jz), sj = rdl(r_sw, jz); \
        float tmpz = zz[jz + 1]; \
        zz[jz + 1] = cj * tmpz - sj * zz[jz]; \
        zz[jz]     = sj * tmpz + cj * zz[jz]; \
    } } while (0)

__global__ __launch_bounds__(64) void eig_kernel(
    const double* __restrict__ partial, float* __restrict__ out)
{
    const int n = 9;
    int b = blockIdx.x;
    int lane = threadIdx.x;

    __shared__ float A[10][10];    // 1-based; lower triangle + reflectors
    __shared__ float Zl[10][10];   // used only for sort/epilogue
    __shared__ float ddl[11], eel[11], tau[10], wv[10], zv[10];

    float zz[10];                  // lane r (1..9) holds Z row r, cols 1..9
    float r_dd, r_ee, r_cw, r_sw;  // lane-distributed ssteqr state

    // ---- load lower triangle: lanes 0..44, sum 4 chunk partials in order ----
    if (lane < 45) {
        const double* p = partial + (size_t)b * (45 * NCHUNK) + lane;
        double s = ((p[0] + p[45]) + p[90]) + p[135];
        int idx = lane, j = 1;
        while (idx >= 10 - j) { idx -= (10 - j); ++j; }
        int i = j + idx;
        A[i][j] = (float)s;
    }

    // ---- ssytd2 ('L') : unchanged from R3 ----
    for (int i = 1; i <= n - 1; ++i) {
        float alpha = A[i + 1][i];
        float ssq = 0.0f;
        for (int k = i + 2; k <= n; ++k) ssq += A[k][i] * A[k][i];
        float xnorm = sqrtf(ssq);
        float taui;
        if (xnorm == 0.0f) {
            taui = 0.0f;
            if (lane == 0) eel[i] = alpha;
        } else {
            float beta = -f_sign(slapy2(alpha, xnorm), alpha);
            taui = (beta - alpha) / beta;
            float sc = 1.0f / (alpha - beta);
            if (lane < 8 - i) {
                int k = i + 2 + lane;
                A[k][i] *= sc;
            }
            if (lane == 0) eel[i] = beta;
        }
        if (taui != 0.0f) {
            if (lane < 9 - i) {
                int r2 = i + 1 + lane;
                float s2 = 0.0f;
                for (int c2 = i + 1; c2 <= n; ++c2) {
                    float aval = (r2 >= c2) ? A[r2][c2] : A[c2][r2];
                    float vc = (c2 == i + 1) ? 1.0f : A[c2][i];
                    s2 += aval * vc;
                }
                wv[r2] = taui * s2;
            }
            float dot = 0.0f;
            for (int k = i + 1; k <= n; ++k) {
                float vk = (k == i + 1) ? 1.0f : A[k][i];
                dot += wv[k] * vk;
            }
            float alpha2 = -0.5f * taui * dot;
            if (lane < 9 - i) {
                int k = i + 1 + lane;
                float vk = (k == i + 1) ? 1.0f : A[k][i];
                wv[k] += alpha2 * vk;
            }
            int kk = 9 - i;
            int cnt = kk * (kk + 1) / 2;
            if (lane < cnt) {
                int idx = lane, cc = 0;
                while (idx >= kk - cc) { idx -= (kk - cc); ++cc; }
                int c2 = i + 1 + cc;
                int r2 = c2 + idx;
                float vr = (r2 == i + 1) ? 1.0f : A[r2][i];
                float vc = (c2 == i + 1) ? 1.0f : A[c2][i];
                A[r2][c2] -= vr * wv[c2] + wv[r2] * vc;
            }
        }
        if (lane == 0) { ddl[i] = A[i][i]; tau[i] = taui; }
    }
    if (lane == 0) ddl[n] = A[n][n];

    // ---- handoff: LDS -> lane-distributed registers ----
    r_dd = 0.0f; r_ee = 0.0f;
    if (lane >= 1 && lane <= 9) r_dd = ddl[lane];
    if (lane >= 1 && lane <= 8) r_ee = eel[lane];

    // ---- Z = I in registers (lane r holds row r) ----
#pragma unroll
    for (int c0 = 1; c0 <= 9; ++c0) zz[c0] = (lane == c0) ? 1.0f : 0.0f;

    // ---- ssteqr ('I') ----
    const float eps    = 5.9604645e-8f;
    const float eps2   = eps * eps;
    const float safmin = 1.17549435e-38f;
    const float safmax = 1.0f / 1.17549435e-38f;
    const float ssfmax = sqrtf(safmax) / 3.0f;
    const float ssfmin = sqrtf(safmin) / eps2;

    int nmaxit = n * 30, jtot = 0;
    int l1 = 1, nm1 = n - 1;
    int l, m, lsv, lend, lendsv, iscale;
    float anorm, p, g, r, c, s, f, btmp, rt1, rt2, tst, mul;

L10:
    if (l1 > n) goto L160;
    if (l1 > 1) r_ee = (lane == l1 - 1) ? 0.0f : r_ee;
    if (l1 <= nm1) {
        for (m = l1; m <= nm1; ++m) {
            tst = fabsf(rdl(r_ee, m));
            if (tst == 0.0f) goto L30;
            if (tst <= (sqrtf(fabsf(rdl(r_dd, m))) * sqrtf(fabsf(rdl(r_dd, m + 1)))) * eps) {
                r_ee = (lane == m) ? 0.0f : r_ee;
                goto L30;
            }
        }
    }
    m = n;
L30:
    l = l1; lsv = l; lend = m; lendsv = lend; l1 = m + 1;
    if (lend == l) goto L10;

    anorm = 0.0f;
    for (int k = l; k <= lend; ++k) anorm = fmaxf(anorm, fabsf(rdl(r_dd, k)));
    for (int k = l; k <= lend - 1; ++k) anorm = fmaxf(anorm, fabsf(rdl(r_ee, k)));
    iscale = 0;
    if (anorm == 0.0f) goto L10;
    if (anorm > ssfmax) {
        iscale = 1; mul = ssfmax / anorm;
        r_dd = (lane >= l && lane <= lend)     ? r_dd * mul : r_dd;
        r_ee = (lane >= l && lane <= lend - 1) ? r_ee * mul : r_ee;
    } else if (anorm < ssfmin) {
        iscale = 2; mul = ssfmin / anorm;
        r_dd = (lane >= l && lane <= lend)     ? r_dd * mul : r_dd;
        r_ee = (lane >= l && lane <= lend - 1) ? r_ee * mul : r_ee;
    }

    if (fabsf(rdl(r_dd, lend)) < fabsf(rdl(r_dd, l))) { lend = lsv; l = lendsv; }

    if (lend > l) {
        // ---------- QL ----------
L40:
        if (l != lend) {
            for (m = l; m <= lend - 1; ++m) {
                tst = fabsf(rdl(r_ee, m)); tst = tst * tst;
                if (tst <= (eps2 * fabsf(rdl(r_dd, m))) * fabsf(rdl(r_dd, m + 1)) + safmin) goto L60;
            }
        }
        m = lend;
L60:
        if (m < lend) r_ee = (lane == m) ? 0.0f : r_ee;
        p = rdl(r_dd, l);
        if (m == l) goto L80;
        if (m == l + 1) {
            slaev2(rdl(r_dd, l), rdl(r_ee, l), rdl(r_dd, l + 1), &rt1, &rt2, &c, &s);
            r_cw = 1.0f; r_sw = 0.0f;
            r_cw = (lane == l) ? c : r_cw;
            r_sw = (lane == l) ? s : r_sw;
            APPLY_QL();
            r_dd = (lane == l) ? rt1 : ((lane == l + 1) ? rt2 : r_dd);
            r_ee = (lane == l) ? 0.0f : r_ee;
            l += 2;
            if (l <= lend) goto L40;
            goto L140;
        }
        if (jtot == nmaxit) goto L140;
        ++jtot;
        g = (rdl(r_dd, l + 1) - p) / (2.0f * rdl(r_ee, l));
        r = slapy2(g, 1.0f);
        g = rdl(r_dd, m) - p + rdl(r_ee, l) / (g + f_sign(r, g));
        s = 1.0f; c = 1.0f; p = 0.0f;
        r_cw = 1.0f; r_sw = 0.0f;        // identity fill for this sweep
        for (int i = m - 1; i >= l; --i) {
            float ei = rdl(r_ee, i);
            f = s * ei; btmp = c * ei;
            slartg(g, f, &c, &s, &r);
            if (i != m - 1) r_ee = (lane == i + 1) ? r : r_ee;
            g = rdl(r_dd, i + 1) - p;
            r = (rdl(r_dd, i) - g) * s + 2.0f * c * btmp;
            p = s * r;
            r_dd = (lane == i + 1) ? (g + p) : r_dd;
            g = c * r - btmp;
            r_cw = (lane == i) ? c : r_cw;
            r_sw = (lane == i) ? (-s) : r_sw;
        }
        APPLY_QL();
        r_dd = (lane == l) ? (r_dd - p) : r_dd;
        r_ee = (lane == l) ? g : r_ee;
        goto L40;
L80:
        r_dd = (lane == l) ? p : r_dd;
        l = l + 1;
        if (l <= lend) goto L40;
        goto L140;
    } else {
        // ---------- QR ----------
L90:
        if (l != lend) {
            for (m = l; m >= lend + 1; --m) {
                tst = fabsf(rdl(r_ee, m - 1)); tst = tst * tst;
                if (tst <= (eps2 * fabsf(rdl(r_dd, m))) * fabsf(rdl(r_dd, m - 1)) + safmin) goto L110;
            }
        }
        m = lend;
L110:
        if (m > lend) r_ee = (lane == m - 1) ? 0.0f : r_ee;
        p = rdl(r_dd, l);
        if (m == l) goto L130;
        if (m == l - 1) {
            slaev2(rdl(r_dd, l - 1), rdl(r_ee, l - 1), rdl(r_dd, l), &rt1, &rt2, &c, &s);
            r_cw = 1.0f; r_sw = 0.0f;
            r_cw = (lane == l - 1) ? c : r_cw;
            r_sw = (lane == l - 1) ? s : r_sw;
            APPLY_QR();
            r_dd = (lane == l - 1) ? rt1 : ((lane == l) ? rt2 : r_dd);
            r_ee = (lane == l - 1) ? 0.0f : r_ee;
            l -= 2;
            if (l >= lend) goto L90;
            goto L140;
        }
        if (jtot == nmaxit) goto L140;
        ++jtot;
        g = (rdl(r_dd, l - 1) - p) / (2.0f * rdl(r_ee, l - 1));
        r = slapy2(g, 1.0f);
        g = rdl(r_dd, m) - p + rdl(r_ee, l - 1) / (g + f_sign(r, g));
        s = 1.0f; c = 1.0f; p = 0.0f;
        r_cw = 1.0f; r_sw = 0.0f;        // identity fill for this sweep
        for (int i = m; i <= l - 1; ++i) {
            float ei = rdl(r_ee, i);
            f = s * ei; btmp = c * ei;
            slartg(g, f, &c, &s, &r);
            if (i != m) r_ee = (lane == i - 1) ? r : r_ee;
            g = rdl(r_dd, i) - p;
            r = (rdl(r_dd, i + 1) - g) * s + 2.0f * c * btmp;
            p = s * r;
            r_dd = (lane == i) ? (g + p) : r_dd;
            g = c * r - btmp;
            r_cw = (lane == i) ? c : r_cw;
            r_sw = (lane == i) ? s : r_sw;
        }
        APPLY_QR();
        r_dd = (lane == l) ? (r_dd - p) : r_dd;
        r_ee = (lane == l - 1) ? g : r_ee;
        goto L90;
L130:
        r_dd = (lane == l) ? p : r_dd;
        l = l - 1;
        if (l >= lend) goto L90;
        goto L140;
    }

L140:
    if (iscale == 1) {
        mul = anorm / ssfmax;
        r_dd = (lane >= lsv && lane <= lendsv)     ? r_dd * mul : r_dd;
        r_ee = (lane >= lsv && lane <= lendsv - 1) ? r_ee * mul : r_ee;
    } else if (iscale == 2) {
        mul = anorm / ssfmin;
        r_dd = (lane >= lsv && lane <= lendsv)     ? r_dd * mul : r_dd;
        r_ee = (lane >= lsv && lane <= lendsv - 1) ? r_ee * mul : r_ee;
    }
    if (jtot < nmaxit) goto L10;
    goto L160;

L160:
    // dump Z registers to LDS for the dynamic-index sort + epilogue
    if (lane >= 1 && lane <= 9) {
#pragma unroll
        for (int c0 = 1; c0 <= 9; ++c0) Zl[lane][c0] = zz[c0];
    }

    // selection sort ascending (strict '<', matches ssteqr)
    for (int ii = 2; ii <= n; ++ii) {
        int i = ii - 1, k = i;
        p = rdl(r_dd, i);
        for (int j = ii; j <= n; ++j) {
            float dj = rdl(r_dd, j);
            if (dj < p) { k = j; p = dj; }
        }
        if (k != i) {
            float di = rdl(r_dd, i);
            r_dd = (lane == k) ? di : r_dd;
            r_dd = (lane == i) ? p  : r_dd;
            if (lane >= 1 && lane <= 9) {
                float t = Zl[lane][i]; Zl[lane][i] = Zl[lane][k]; Zl[lane][k] = t;
            }
        }
    }

    // ---- apply Q (sormtr 'L','L','N') to Z(:,1), then normalize ----
    if (lane < 9) zv[lane + 1] = Zl[lane + 1][1];
    for (int i2 = n - 1; i2 >= 1; --i2) {
        float ti = tau[i2];
        if (ti != 0.0f) {
            float dotp = zv[i2 + 1];
            for (int k = i2 + 2; k <= n; ++k) dotp += A[k][i2] * zv[k];
            float t = ti * dotp;
            if (lane < 9 - i2) {
                int k = i2 + 1 + lane;
                float upd = (k == i2 + 1) ? t : t * A[k][i2];
                zv[k] -= upd;
            }
        }
    }
    {
        float nrm = 0.0f;
        for (int row = 1; row <= n; ++row) nrm += zv[row] * zv[row];
        nrm = sqrtf(nrm);
        if (lane < 9) out[(size_t)b * 9 + lane] = zv[lane + 1] / nrm;
    }
}

extern "C" void kernel_launch(void* const* d_in, const int* in_sizes, int n_in,
                              void* d_out, int out_size, void* d_ws, size_t ws_size,
                              hipStream_t stream) {
    const float4* x = (const float4*)d_in[0];   // (256,1,20000,4) f32
    const float*  w = (const float*)d_in[1];    // (256,20000) f32
    float* out = (float*)d_out;                 // (256,9) f32
    double* partial = (double*)d_ws;            // 256*4*45 doubles = 368640 B

    gram_kernel<<<dim3(BATCH, NCHUNK), dim3(256), 0, stream>>>(x, w, partial);
    eig_kernel<<<dim3(BATCH), dim3(64), 0, stream>>>(partial, out);
}